// Round 1
// baseline (147.128 us; speedup 1.0000x reference)
//
#include <hip/hip_runtime.h>

// NeuralOoOScheduler: B=8192, W=64. Embedding path in the reference is dead
// (del emb) — only the hazard dep_matrix + readiness are live.
// Write-bound: 134 MB dep_matrix + 2 MB readiness out, 2 MB instructions in.

constexpr int Bv = 8192;
constexpr int Wv = 64;

__global__ __launch_bounds__(256) void ooo_kernel(
    const int* __restrict__ inst,
    const float* __restrict__ hw,
    float* __restrict__ dep,
    float* __restrict__ ready)
{
    const int b   = blockIdx.x;
    const int tid = threadIdx.x;

    __shared__ int   s_rd[Wv], s_rn[Wv], s_rm[Wv];
    __shared__ float s_part[16 * Wv];   // [i-group][j] partial readiness products

    if (tid < Wv) {
        int v = inst[(size_t)b * Wv + tid];
        s_rd[tid] = v & 31;
        s_rn[tid] = (v >> 5) & 31;
        s_rm[tid] = (v >> 16) & 31;
    }

    // score = h0*raw + h2*waw + h4  ->  only 4 distinct sigmoid values
    const float h0 = hw[0], h2 = hw[2], h4 = hw[4];
    const float v00 = 1.f / (1.f + __expf(-(h4)));            // raw=0 waw=0
    const float v10 = 1.f / (1.f + __expf(-(h0 + h4)));       // raw=1 waw=0
    const float v01 = 1.f / (1.f + __expf(-(h2 + h4)));       // raw=0 waw=1
    const float v11 = 1.f / (1.f + __expf(-(h0 + h2 + h4)));  // raw=1 waw=1

    __syncthreads();

    // thread -> j in [jb, jb+4), i in {ig + 16k}; a wave's float4 stores cover
    // 4 consecutive i-rows = 1 KiB contiguous per store instruction.
    const int jb = (tid & 15) << 2;
    const int ig = tid >> 4;

    int  rdj[4], rnj[4], rmj[4];
    bool jv[4];
#pragma unroll
    for (int q = 0; q < 4; ++q) {
        rdj[q] = s_rd[jb + q];
        rnj[q] = s_rn[jb + q];
        rmj[q] = s_rm[jb + q];
        jv[q]  = rdj[q] < 31;
    }

    float prod[4] = {1.f, 1.f, 1.f, 1.f};
    float* const dep_row = dep + (size_t)b * Wv * Wv;

#pragma unroll
    for (int k = 0; k < 4; ++k) {
        const int  i   = ig + 16 * k;
        const int  rdi = s_rd[i];
        const bool iv  = rdi < 31;
        float o[4];
#pragma unroll
        for (int q = 0; q < 4; ++q) {
            const int  j   = jb + q;
            const bool raw = iv && ((rdi == rnj[q]) || (rdi == rmj[q]));
            const bool waw = iv && jv[q] && (rdi == rdj[q]);
            float val = waw ? (raw ? v11 : v01) : (raw ? v10 : v00);
            float d   = (j > i) ? val : 0.f;
            o[q] = d;
            prod[q] *= (1.f - d);
        }
        *(float4*)(dep_row + i * Wv + jb) =
            make_float4(o[0], o[1], o[2], o[3]);
    }

    // readiness[j] = prod over all 16 i-groups
    s_part[ig * Wv + jb + 0] = prod[0];
    s_part[ig * Wv + jb + 1] = prod[1];
    s_part[ig * Wv + jb + 2] = prod[2];
    s_part[ig * Wv + jb + 3] = prod[3];
    __syncthreads();

    if (tid < Wv) {
        float r = 1.f;
#pragma unroll
        for (int g = 0; g < 16; ++g) r *= s_part[g * Wv + tid];
        ready[(size_t)b * Wv + tid] = r;
    }
}

extern "C" void kernel_launch(void* const* d_in, const int* in_sizes, int n_in,
                              void* d_out, int out_size, void* d_ws, size_t ws_size,
                              hipStream_t stream) {
    const int*   instructions   = (const int*)d_in[0];
    const float* hazard_weights = (const float*)d_in[5];

    float* dep   = (float*)d_out;                      // (B, W, W)
    float* ready = dep + (size_t)Bv * Wv * Wv;         // (B, W)

    ooo_kernel<<<Bv, 256, 0, stream>>>(instructions, hazard_weights, dep, ready);
}